// Round 5
// baseline (626.270 us; speedup 1.0000x reference)
//
#include <hip/hip_runtime.h>

namespace {

constexpr int B = 2;
constexpr int N = 200000;
constexpr int C = 16;
constexpr int D = 256;
constexpr int H = 256;
constexpr int W = 32;
constexpr int V = D * H * W;    // 2^21 voxels per batch
constexpr int BV = B * V;       // 4,194,304
constexpr unsigned NIL = 0xFFFFFFFFu;
constexpr int VOX = 512;        // voxels per finalize block (32 KB LDS tile)

// Replicate reference op order exactly: (p - lo) / (hi - lo) * dim, trunc, clip.
// (This exact formulation gave absmax 0 across all rounds — do not change.)
__device__ __forceinline__ int voxel_of(float x, float y, float z) {
    float fx = (x - (-48.0f)) / 96.0f * 256.0f;
    float fy = (y - (-48.0f)) / 96.0f * 256.0f;
    float fz = (z - (-4.0f)) / 5.5f * 32.0f;
    int vx = (int)fx;
    int vy = (int)fy;
    int vz = (int)fz;
    vx = vx < 0 ? 0 : (vx > D - 1 ? D - 1 : vx);
    vy = vy < 0 ? 0 : (vy > H - 1 ? H - 1 : vy);
    vz = vz < 0 ? 0 : (vz > W - 1 ? W - 1 : vz);
    return (vx * H + vy) * W + vz;
}

// NOTE: no __builtin_nontemporal_* anywhere (kills head/nxt L2 hits).
// NOTE (R2 lesson): cooperative fusion regressed. Keep 3 plain kernels.
// NOTE (R4/R5): DIFFERENTIAL MEASUREMENT ROUND (R4 attempt died to infra,
// resubmitted verbatim). finalize_tile launched 5x (idempotent overwrite)
// to expose T_finalize = (dur_us - 334.8) / 4. Kernels byte-identical to R3.

__global__ __launch_bounds__(256) void init_head(uint4* __restrict__ head4, int n4) {
    int i = blockIdx.x * blockDim.x + threadIdx.x;
    if (i < n4) head4[i] = make_uint4(NIL, NIL, NIL, NIL);
}

// One atomicExch per point: push point idx onto its voxel's intrusive list.
__global__ __launch_bounds__(256) void build_list(
    const float* __restrict__ pts, unsigned* __restrict__ head,
    unsigned* __restrict__ nxt) {
    int idx = blockIdx.x * blockDim.x + threadIdx.x;
    if (idx >= B * N) return;
    const float* p = pts + (size_t)idx * 3;
    int v = voxel_of(p[0], p[1], p[2]);
    int b = idx >= N ? 1 : 0;   // B == 2
    unsigned old = atomicExch(head + (size_t)b * V + v, (unsigned)idx);
    nxt[idx] = old;
}

// R3 finalize: gather 512 voxels into a channel-major LDS tile, then stream
// each channel out as a 2 KB contiguous burst (wave w owns channels 4w..4w+3).
__global__ __launch_bounds__(256) void finalize_tile(
    const unsigned* __restrict__ head, const unsigned* __restrict__ nxt,
    const float4* __restrict__ fts4, float* __restrict__ out) {
    __shared__ float tile[C][VOX];          // 32 KB -> 4-5 blocks/CU

    const int tid = threadIdx.x;
    const int base = blockIdx.x * VOX;      // flat (b,v); VOX | V so no straddle
    const int b = base >> 21;               // V = 2^21
    const int v0 = base & (V - 1);

    // ---- Phase A: gather. 2 voxels per thread; issue both head loads first.
    unsigned h[2];
    h[0] = head[base + tid];
    h[1] = head[base + 256 + tid];

#pragma unroll
    for (int k = 0; k < 2; ++k) {
        float s[16];
#pragma unroll
        for (int c = 0; c < 16; ++c) s[c] = 0.f;
        float cnt = 0.f;
        unsigned nx = NIL;

        if (h[k] != NIL) {                  // ~9.1% of lanes
            const float4* fp = fts4 + (size_t)h[k] * 4;
            float4 f0 = fp[0];
            float4 f1 = fp[1];
            float4 f2 = fp[2];
            float4 f3 = fp[3];              // one 64B line, fully used
            nx = nxt[h[k]];
            s[0]  = f0.x; s[1]  = f0.y; s[2]  = f0.z; s[3]  = f0.w;
            s[4]  = f1.x; s[5]  = f1.y; s[6]  = f1.z; s[7]  = f1.w;
            s[8]  = f2.x; s[9]  = f2.y; s[10] = f2.z; s[11] = f2.w;
            s[12] = f3.x; s[13] = f3.y; s[14] = f3.z; s[15] = f3.w;
            cnt = 1.f;
        }

        // Rare tail: voxels with >= 2 points.
        while (nx != NIL) {
            const float4* fp = fts4 + (size_t)nx * 4;
            float4 f0 = fp[0];
            float4 f1 = fp[1];
            float4 f2 = fp[2];
            float4 f3 = fp[3];
            unsigned nn = nxt[nx];
            s[0]  += f0.x; s[1]  += f0.y; s[2]  += f0.z; s[3]  += f0.w;
            s[4]  += f1.x; s[5]  += f1.y; s[6]  += f1.z; s[7]  += f1.w;
            s[8]  += f2.x; s[9]  += f2.y; s[10] += f2.z; s[11] += f2.w;
            s[12] += f3.x; s[13] += f3.y; s[14] += f3.z; s[15] += f3.w;
            cnt += 1.f;
            nx = nn;
        }

        if (cnt > 1.f) {                    // cnt==1: s/1 is exact, skip div
            float c = cnt;
#pragma unroll
            for (int q = 0; q < 16; ++q) s[q] /= c;
        }

        // Channel-major LDS write. addr = c*512 + idx: bank = idx%32 for all
        // c (512%32==0), lanes consecutive -> 2 lanes/bank (free on wave64).
        int idx = k * 256 + tid;
#pragma unroll
        for (int c = 0; c < 16; ++c) tile[c][idx] = s[c];
    }

    __syncthreads();

    // ---- Phase B: stream out. Wave w owns channels 4w..4w+3; per channel
    // writes VOX*4B = 2 KB contiguous (2 x float4 per lane).
    const int w = tid >> 6;
    const int l = tid & 63;
    float* obase = out + (size_t)b * C * V + v0;
#pragma unroll
    for (int cc = 0; cc < 4; ++cc) {
        int c = w * 4 + cc;
#pragma unroll
        for (int k = 0; k < VOX / 256; ++k) {   // 2 float4 instrs per channel
            int idx = k * 64 + l;               // float4 index within channel
            float4 val = *(const float4*)&tile[c][idx * 4];
            *(float4*)(obase + (size_t)c * V + idx * 4) = val;
        }
    }
}

// ---- Fallback (tiny-workspace safety net): direct strided atomics into out.
__global__ __launch_bounds__(256) void zero_f4(float4* __restrict__ p, int n4) {
    int i = blockIdx.x * blockDim.x + threadIdx.x;
    if (i < n4) p[i] = make_float4(0.f, 0.f, 0.f, 0.f);
}

__global__ __launch_bounds__(256) void count_only(
    const float* __restrict__ pts, float* __restrict__ counts) {
    int idx = blockIdx.x * blockDim.x + threadIdx.x;
    if (idx >= B * N) return;
    int b = idx >= N ? 1 : 0;
    const float* p = pts + (size_t)idx * 3;
    int v = voxel_of(p[0], p[1], p[2]);
    atomicAdd(counts + (size_t)b * V + v, 1.0f);
}

__global__ __launch_bounds__(256) void scatter_direct(
    const float* __restrict__ pts, const float* __restrict__ fts,
    const float* __restrict__ counts, float* __restrict__ out) {
    int idx = blockIdx.x * blockDim.x + threadIdx.x;
    if (idx >= B * N) return;
    int b = idx >= N ? 1 : 0;
    const float* p = pts + (size_t)idx * 3;
    int v = voxel_of(p[0], p[1], p[2]);
    float cnt = counts[(size_t)b * V + v];
    const float* f = fts + (size_t)idx * C;
    float* o = out + (size_t)b * C * V + v;
#pragma unroll
    for (int c = 0; c < 16; ++c) atomicAdd(o + (size_t)c * V, f[c] / cnt);
}

}  // namespace

extern "C" void kernel_launch(void* const* d_in, const int* in_sizes, int n_in,
                              void* d_out, int out_size, void* d_ws, size_t ws_size,
                              hipStream_t stream) {
    const float* pts = (const float*)d_in[0];   // [B, N, 3]
    const float* fts = (const float*)d_in[1];   // [B, N, C]
    float* out = (float*)d_out;                 // [B, C, D, H, W]

    const int n_pts = B * N;                    // 400,000
    const int pt_blocks = (n_pts + 255) / 256;

    const size_t head_bytes = (size_t)BV * sizeof(unsigned);      // 16.8 MB
    const size_t nxt_bytes = (size_t)n_pts * sizeof(unsigned);    // 1.6 MB

    if (ws_size >= head_bytes + nxt_bytes) {
        unsigned* head = (unsigned*)d_ws;
        unsigned* nxt = head + (size_t)BV;

        int head_n4 = BV / 4;  // 1,048,576
        init_head<<<(head_n4 + 255) / 256, 256, 0, stream>>>((uint4*)head, head_n4);
        build_list<<<pt_blocks, 256, 0, stream>>>(pts, head, nxt);

        // DIFFERENTIAL MEASUREMENT: finalize_tile is a pure function of
        // (head, nxt, fts) overwriting out with identical values — launching
        // it 5x is result-identical. T_finalize = (dur_us - 334.8) / 4.
        int fin_blocks = BV / VOX;  // 8192
        for (int r = 0; r < 5; ++r)
            finalize_tile<<<fin_blocks, 256, 0, stream>>>(
                head, nxt, (const float4*)fts, out);
    } else {
        // Safety net: direct atomic accumulation into out.
        float* counts = (float*)d_ws;
        int counts_f4 = BV / 4;
        zero_f4<<<(counts_f4 + 255) / 256, 256, 0, stream>>>((float4*)counts, counts_f4);
        int out_f4 = out_size / 4;
        zero_f4<<<(out_f4 + 255) / 256, 256, 0, stream>>>((float4*)out, out_f4);
        count_only<<<pt_blocks, 256, 0, stream>>>(pts, counts);
        scatter_direct<<<pt_blocks, 256, 0, stream>>>(pts, fts, counts, out);
    }
}

// Round 6
// 423.695 us; speedup vs baseline: 1.4781x; 1.4781x over previous
//
#include <hip/hip_runtime.h>

namespace {

constexpr int B = 2;
constexpr int N = 200000;
constexpr int C = 16;
constexpr int D = 256;
constexpr int H = 256;
constexpr int W = 32;
constexpr int V = D * H * W;    // 2^21 voxels per batch
constexpr int BV = B * V;       // 4,194,304
constexpr unsigned NIL = 0xFFFFFFFFu;
constexpr int VOX = 512;        // voxels per finalize block (32 KB LDS tile)

// Replicate reference op order exactly: (p - lo) / (hi - lo) * dim, trunc, clip.
// (This exact formulation gave absmax 0 across all rounds — do not change.)
__device__ __forceinline__ int voxel_of(float x, float y, float z) {
    float fx = (x - (-48.0f)) / 96.0f * 256.0f;
    float fy = (y - (-48.0f)) / 96.0f * 256.0f;
    float fz = (z - (-4.0f)) / 5.5f * 32.0f;
    int vx = (int)fx;
    int vy = (int)fy;
    int vz = (int)fz;
    vx = vx < 0 ? 0 : (vx > D - 1 ? D - 1 : vx);
    vy = vy < 0 ? 0 : (vy > H - 1 ? H - 1 : vy);
    vz = vz < 0 ? 0 : (vz > W - 1 ? W - 1 : vz);
    return (vx * H + vy) * W + vz;
}

// NOTE: no __builtin_nontemporal_* anywhere (kills head/nxt L2 hits).
// NOTE (R2 lesson): cooperative fusion regressed. Keep 3 plain kernels.
// MEASUREMENT LEDGER (differential timing, both with kernels byte-identical
// to R3):
//   R5: finalize x5            -> T_finalize ~= 72.9 us
//   R6 (this): (init+build) x5 -> T_init+build = (dur - 334.8) / 4
// The pair init+build is idempotent (init fully resets head; build rewrites
// every nxt entry); finalize runs once on the 5th build's state.

__global__ __launch_bounds__(256) void init_head(uint4* __restrict__ head4, int n4) {
    int i = blockIdx.x * blockDim.x + threadIdx.x;
    if (i < n4) head4[i] = make_uint4(NIL, NIL, NIL, NIL);
}

// One atomicExch per point: push point idx onto its voxel's intrusive list.
__global__ __launch_bounds__(256) void build_list(
    const float* __restrict__ pts, unsigned* __restrict__ head,
    unsigned* __restrict__ nxt) {
    int idx = blockIdx.x * blockDim.x + threadIdx.x;
    if (idx >= B * N) return;
    const float* p = pts + (size_t)idx * 3;
    int v = voxel_of(p[0], p[1], p[2]);
    int b = idx >= N ? 1 : 0;   // B == 2
    unsigned old = atomicExch(head + (size_t)b * V + v, (unsigned)idx);
    nxt[idx] = old;
}

// R3 finalize: gather 512 voxels into a channel-major LDS tile, then stream
// each channel out as a 2 KB contiguous burst (wave w owns channels 4w..4w+3).
__global__ __launch_bounds__(256) void finalize_tile(
    const unsigned* __restrict__ head, const unsigned* __restrict__ nxt,
    const float4* __restrict__ fts4, float* __restrict__ out) {
    __shared__ float tile[C][VOX];          // 32 KB -> 4-5 blocks/CU

    const int tid = threadIdx.x;
    const int base = blockIdx.x * VOX;      // flat (b,v); VOX | V so no straddle
    const int b = base >> 21;               // V = 2^21
    const int v0 = base & (V - 1);

    // ---- Phase A: gather. 2 voxels per thread; issue both head loads first.
    unsigned h[2];
    h[0] = head[base + tid];
    h[1] = head[base + 256 + tid];

#pragma unroll
    for (int k = 0; k < 2; ++k) {
        float s[16];
#pragma unroll
        for (int c = 0; c < 16; ++c) s[c] = 0.f;
        float cnt = 0.f;
        unsigned nx = NIL;

        if (h[k] != NIL) {                  // ~9.1% of lanes
            const float4* fp = fts4 + (size_t)h[k] * 4;
            float4 f0 = fp[0];
            float4 f1 = fp[1];
            float4 f2 = fp[2];
            float4 f3 = fp[3];              // one 64B line, fully used
            nx = nxt[h[k]];
            s[0]  = f0.x; s[1]  = f0.y; s[2]  = f0.z; s[3]  = f0.w;
            s[4]  = f1.x; s[5]  = f1.y; s[6]  = f1.z; s[7]  = f1.w;
            s[8]  = f2.x; s[9]  = f2.y; s[10] = f2.z; s[11] = f2.w;
            s[12] = f3.x; s[13] = f3.y; s[14] = f3.z; s[15] = f3.w;
            cnt = 1.f;
        }

        // Rare tail: voxels with >= 2 points.
        while (nx != NIL) {
            const float4* fp = fts4 + (size_t)nx * 4;
            float4 f0 = fp[0];
            float4 f1 = fp[1];
            float4 f2 = fp[2];
            float4 f3 = fp[3];
            unsigned nn = nxt[nx];
            s[0]  += f0.x; s[1]  += f0.y; s[2]  += f0.z; s[3]  += f0.w;
            s[4]  += f1.x; s[5]  += f1.y; s[6]  += f1.z; s[7]  += f1.w;
            s[8]  += f2.x; s[9]  += f2.y; s[10] += f2.z; s[11] += f2.w;
            s[12] += f3.x; s[13] += f3.y; s[14] += f3.z; s[15] += f3.w;
            cnt += 1.f;
            nx = nn;
        }

        if (cnt > 1.f) {                    // cnt==1: s/1 is exact, skip div
            float c = cnt;
#pragma unroll
            for (int q = 0; q < 16; ++q) s[q] /= c;
        }

        // Channel-major LDS write. addr = c*512 + idx: bank = idx%32 for all
        // c (512%32==0), lanes consecutive -> 2 lanes/bank (free on wave64).
        int idx = k * 256 + tid;
#pragma unroll
        for (int c = 0; c < 16; ++c) tile[c][idx] = s[c];
    }

    __syncthreads();

    // ---- Phase B: stream out. Wave w owns channels 4w..4w+3; per channel
    // writes VOX*4B = 2 KB contiguous (2 x float4 per lane).
    const int w = tid >> 6;
    const int l = tid & 63;
    float* obase = out + (size_t)b * C * V + v0;
#pragma unroll
    for (int cc = 0; cc < 4; ++cc) {
        int c = w * 4 + cc;
#pragma unroll
        for (int k = 0; k < VOX / 256; ++k) {   // 2 float4 instrs per channel
            int idx = k * 64 + l;               // float4 index within channel
            float4 val = *(const float4*)&tile[c][idx * 4];
            *(float4*)(obase + (size_t)c * V + idx * 4) = val;
        }
    }
}

// ---- Fallback (tiny-workspace safety net): direct strided atomics into out.
__global__ __launch_bounds__(256) void zero_f4(float4* __restrict__ p, int n4) {
    int i = blockIdx.x * blockDim.x + threadIdx.x;
    if (i < n4) p[i] = make_float4(0.f, 0.f, 0.f, 0.f);
}

__global__ __launch_bounds__(256) void count_only(
    const float* __restrict__ pts, float* __restrict__ counts) {
    int idx = blockIdx.x * blockDim.x + threadIdx.x;
    if (idx >= B * N) return;
    int b = idx >= N ? 1 : 0;
    const float* p = pts + (size_t)idx * 3;
    int v = voxel_of(p[0], p[1], p[2]);
    atomicAdd(counts + (size_t)b * V + v, 1.0f);
}

__global__ __launch_bounds__(256) void scatter_direct(
    const float* __restrict__ pts, const float* __restrict__ fts,
    const float* __restrict__ counts, float* __restrict__ out) {
    int idx = blockIdx.x * blockDim.x + threadIdx.x;
    if (idx >= B * N) return;
    int b = idx >= N ? 1 : 0;
    const float* p = pts + (size_t)idx * 3;
    int v = voxel_of(p[0], p[1], p[2]);
    float cnt = counts[(size_t)b * V + v];
    const float* f = fts + (size_t)idx * C;
    float* o = out + (size_t)b * C * V + v;
#pragma unroll
    for (int c = 0; c < 16; ++c) atomicAdd(o + (size_t)c * V, f[c] / cnt);
}

}  // namespace

extern "C" void kernel_launch(void* const* d_in, const int* in_sizes, int n_in,
                              void* d_out, int out_size, void* d_ws, size_t ws_size,
                              hipStream_t stream) {
    const float* pts = (const float*)d_in[0];   // [B, N, 3]
    const float* fts = (const float*)d_in[1];   // [B, N, C]
    float* out = (float*)d_out;                 // [B, C, D, H, W]

    const int n_pts = B * N;                    // 400,000
    const int pt_blocks = (n_pts + 255) / 256;

    const size_t head_bytes = (size_t)BV * sizeof(unsigned);      // 16.8 MB
    const size_t nxt_bytes = (size_t)n_pts * sizeof(unsigned);    // 1.6 MB

    if (ws_size >= head_bytes + nxt_bytes) {
        unsigned* head = (unsigned*)d_ws;
        unsigned* nxt = head + (size_t)BV;

        // DIFFERENTIAL MEASUREMENT #2: (init_head + build_list) x5.
        // Pair is idempotent; the 5th build leaves valid fresh list state.
        // T_init+build = (dur_us - 334.8) / 4.
        int head_n4 = BV / 4;  // 1,048,576
        for (int r = 0; r < 5; ++r) {
            init_head<<<(head_n4 + 255) / 256, 256, 0, stream>>>(
                (uint4*)head, head_n4);
            build_list<<<pt_blocks, 256, 0, stream>>>(pts, head, nxt);
        }

        int fin_blocks = BV / VOX;  // 8192
        finalize_tile<<<fin_blocks, 256, 0, stream>>>(
            head, nxt, (const float4*)fts, out);
    } else {
        // Safety net: direct atomic accumulation into out.
        float* counts = (float*)d_ws;
        int counts_f4 = BV / 4;
        zero_f4<<<(counts_f4 + 255) / 256, 256, 0, stream>>>((float4*)counts, counts_f4);
        int out_f4 = out_size / 4;
        zero_f4<<<(out_f4 + 255) / 256, 256, 0, stream>>>((float4*)out, out_f4);
        count_only<<<pt_blocks, 256, 0, stream>>>(pts, counts);
        scatter_direct<<<pt_blocks, 256, 0, stream>>>(pts, fts, counts, out);
    }
}

// Round 7
// 329.703 us; speedup vs baseline: 1.8995x; 1.2851x over previous
//
#include <hip/hip_runtime.h>

namespace {

constexpr int B = 2;
constexpr int N = 200000;
constexpr int C = 16;
constexpr int D = 256;
constexpr int H = 256;
constexpr int W = 32;
constexpr int V = D * H * W;    // 2^21 voxels per batch
constexpr int BV = B * V;       // 4,194,304
constexpr unsigned NIL = 0xFFFFFFFFu;

// Replicate reference op order exactly: (p - lo) / (hi - lo) * dim, trunc, clip.
// (This exact formulation gave absmax 0 across all rounds — do not change.)
__device__ __forceinline__ int voxel_of(float x, float y, float z) {
    float fx = (x - (-48.0f)) / 96.0f * 256.0f;
    float fy = (y - (-48.0f)) / 96.0f * 256.0f;
    float fz = (z - (-4.0f)) / 5.5f * 32.0f;
    int vx = (int)fx;
    int vy = (int)fy;
    int vz = (int)fz;
    vx = vx < 0 ? 0 : (vx > D - 1 ? D - 1 : vx);
    vy = vy < 0 ? 0 : (vy > H - 1 ? H - 1 : vy);
    vz = vz < 0 ? 0 : (vz > W - 1 ? W - 1 : vz);
    return (vx * H + vy) * W + vz;
}

// ============================ SESSION LEDGER =============================
// Differential timing (R5: finalize x5; R6: (init+build) x5) decomposed
// dur_us = 334.8 into:
//   harness fixed term (ws/out poison fills + dispatch): ~239.7 us
//   finalize:    72.9 us  (341 MB traffic -> 4.7 TB/s effective)
//   init+build:  22.2 us
// Falsified theories (all neutral within +/-5 us):
//   R1: finalize occupancy/ILP restructure (1 thr/voxel, full occupancy)
//   R2: cooperative 3-phase fusion (REGRESSED: 438 us in-kernel @16 waves/CU)
//   R3: LDS-tile channel-major 2KB-burst writes (DRAM row-thrash theory)
// R2 counters: FETCH 49 MB / WRITE 286 MB = hand-computed minimum traffic.
// Conclusion: controllable kernels sit at the demonstrated mixed-stream BW
// ceiling (~4.7 TB/s for 268MB strided write + random gather + list reads);
// composition floor ~305-310 us. This file restores the best-measured
// variant (R0 stack, 327.5/329.1 us): 4-voxel-ILP finalize.
// NOTE: no __builtin_nontemporal_* anywhere (kills head/nxt L2 hits; NT
// stores amplified WRITE_SIZE). Keep 3 plain kernels.
// ========================================================================

__global__ __launch_bounds__(256) void init_head(uint4* __restrict__ head4, int n4) {
    int i = blockIdx.x * blockDim.x + threadIdx.x;
    if (i < n4) head4[i] = make_uint4(NIL, NIL, NIL, NIL);
}

// One atomicExch per point: push point idx onto its voxel's intrusive list.
__global__ __launch_bounds__(256) void build_list(
    const float* __restrict__ pts, unsigned* __restrict__ head,
    unsigned* __restrict__ nxt) {
    int idx = blockIdx.x * blockDim.x + threadIdx.x;
    if (idx >= B * N) return;
    const float* p = pts + (size_t)idx * 3;
    int v = voxel_of(p[0], p[1], p[2]);
    int b = idx >= N ? 1 : 0;   // B == 2
    unsigned old = atomicExch(head + (size_t)b * V + v, (unsigned)idx);
    nxt[idx] = old;
}

// One thread per 4 consecutive voxels. Fast path for all-empty (~68% of
// threads). Occupied voxels issue their first-element feature + nxt loads
// up front (MLP); the rare (~5% of occupied) count>=2 tail loops after.
__global__ __launch_bounds__(256) void finalize(
    const uint4* __restrict__ head4, const unsigned* __restrict__ nxt,
    const float4* __restrict__ fts4, float* __restrict__ out) {
    int g = blockIdx.x * blockDim.x + threadIdx.x;
    if (g >= BV / 4) return;
    uint4 h4 = head4[g];
    int t0 = g * 4;               // first (b,v) flat index of this group
    int b = t0 >> 21;             // V = 2^21
    int v = t0 & (V - 1);
    float* obase = out + (size_t)b * C * V + v;

    // AND == all-ones iff every head is NIL.
    if ((h4.x & h4.y & h4.z & h4.w) == NIL) {
        float4 z = make_float4(0.f, 0.f, 0.f, 0.f);
#pragma unroll
        for (int c = 0; c < 16; ++c)
            *(float4*)(obase + (size_t)c * V) = z;
        return;
    }

    unsigned hs[4] = {h4.x, h4.y, h4.z, h4.w};
    float s[4][16];
    float cnt[4];
    unsigned nx[4];

#pragma unroll
    for (int j = 0; j < 4; ++j) {
        cnt[j] = 0.f;
#pragma unroll
        for (int c = 0; c < 16; ++c) s[j][c] = 0.f;
        nx[j] = NIL;
        if (hs[j] != NIL) {
            const float4* fp = fts4 + (size_t)hs[j] * 4;
            float4 f0 = fp[0];
            float4 f1 = fp[1];
            float4 f2 = fp[2];
            float4 f3 = fp[3];
            nx[j] = nxt[hs[j]];
            s[j][0]  = f0.x; s[j][1]  = f0.y; s[j][2]  = f0.z; s[j][3]  = f0.w;
            s[j][4]  = f1.x; s[j][5]  = f1.y; s[j][6]  = f1.z; s[j][7]  = f1.w;
            s[j][8]  = f2.x; s[j][9]  = f2.y; s[j][10] = f2.z; s[j][11] = f2.w;
            s[j][12] = f3.x; s[j][13] = f3.y; s[j][14] = f3.z; s[j][15] = f3.w;
            cnt[j] = 1.f;
        }
    }

    // Rare tail: voxels with >= 2 points.
    while (nx[0] != NIL || nx[1] != NIL || nx[2] != NIL || nx[3] != NIL) {
#pragma unroll
        for (int j = 0; j < 4; ++j) {
            unsigned h = nx[j];
            if (h != NIL) {
                const float4* fp = fts4 + (size_t)h * 4;
                float4 f0 = fp[0];
                float4 f1 = fp[1];
                float4 f2 = fp[2];
                float4 f3 = fp[3];
                nx[j] = nxt[h];
                s[j][0]  += f0.x; s[j][1]  += f0.y; s[j][2]  += f0.z; s[j][3]  += f0.w;
                s[j][4]  += f1.x; s[j][5]  += f1.y; s[j][6]  += f1.z; s[j][7]  += f1.w;
                s[j][8]  += f2.x; s[j][9]  += f2.y; s[j][10] += f2.z; s[j][11] += f2.w;
                s[j][12] += f3.x; s[j][13] += f3.y; s[j][14] += f3.z; s[j][15] += f3.w;
                cnt[j] += 1.f;
            }
        }
    }

#pragma unroll
    for (int j = 0; j < 4; ++j) {
        if (cnt[j] > 1.f) {   // cnt==1: s/1 is exact, skip IEEE div
            float c = cnt[j];
#pragma unroll
            for (int k = 0; k < 16; ++k) s[j][k] /= c;
        }
    }

#pragma unroll
    for (int c = 0; c < 16; ++c) {
        float4 o = make_float4(s[0][c], s[1][c], s[2][c], s[3][c]);
        *(float4*)(obase + (size_t)c * V) = o;
    }
}

// ---- Fallback (tiny-workspace safety net): direct strided atomics into out.
__global__ __launch_bounds__(256) void zero_f4(float4* __restrict__ p, int n4) {
    int i = blockIdx.x * blockDim.x + threadIdx.x;
    if (i < n4) p[i] = make_float4(0.f, 0.f, 0.f, 0.f);
}

__global__ __launch_bounds__(256) void count_only(
    const float* __restrict__ pts, float* __restrict__ counts) {
    int idx = blockIdx.x * blockDim.x + threadIdx.x;
    if (idx >= B * N) return;
    int b = idx >= N ? 1 : 0;
    const float* p = pts + (size_t)idx * 3;
    int v = voxel_of(p[0], p[1], p[2]);
    atomicAdd(counts + (size_t)b * V + v, 1.0f);
}

__global__ __launch_bounds__(256) void scatter_direct(
    const float* __restrict__ pts, const float* __restrict__ fts,
    const float* __restrict__ counts, float* __restrict__ out) {
    int idx = blockIdx.x * blockDim.x + threadIdx.x;
    if (idx >= B * N) return;
    int b = idx >= N ? 1 : 0;
    const float* p = pts + (size_t)idx * 3;
    int v = voxel_of(p[0], p[1], p[2]);
    float cnt = counts[(size_t)b * V + v];
    const float* f = fts + (size_t)idx * C;
    float* o = out + (size_t)b * C * V + v;
#pragma unroll
    for (int c = 0; c < 16; ++c) atomicAdd(o + (size_t)c * V, f[c] / cnt);
}

}  // namespace

extern "C" void kernel_launch(void* const* d_in, const int* in_sizes, int n_in,
                              void* d_out, int out_size, void* d_ws, size_t ws_size,
                              hipStream_t stream) {
    const float* pts = (const float*)d_in[0];   // [B, N, 3]
    const float* fts = (const float*)d_in[1];   // [B, N, C]
    float* out = (float*)d_out;                 // [B, C, D, H, W]

    const int n_pts = B * N;                    // 400,000
    const int pt_blocks = (n_pts + 255) / 256;

    const size_t head_bytes = (size_t)BV * sizeof(unsigned);      // 16.8 MB
    const size_t nxt_bytes = (size_t)n_pts * sizeof(unsigned);    // 1.6 MB

    if (ws_size >= head_bytes + nxt_bytes) {
        unsigned* head = (unsigned*)d_ws;
        unsigned* nxt = head + (size_t)BV;

        int head_n4 = BV / 4;  // 1,048,576
        init_head<<<(head_n4 + 255) / 256, 256, 0, stream>>>((uint4*)head, head_n4);
        build_list<<<pt_blocks, 256, 0, stream>>>(pts, head, nxt);

        int fin_threads = BV / 4;  // 1,048,576 (one per 4 voxels)
        finalize<<<(fin_threads + 255) / 256, 256, 0, stream>>>(
            (const uint4*)head, nxt, (const float4*)fts, out);
    } else {
        // Safety net: direct atomic accumulation into out.
        float* counts = (float*)d_ws;
        int counts_f4 = BV / 4;
        zero_f4<<<(counts_f4 + 255) / 256, 256, 0, stream>>>((float4*)counts, counts_f4);
        int out_f4 = out_size / 4;
        zero_f4<<<(out_f4 + 255) / 256, 256, 0, stream>>>((float4*)out, out_f4);
        count_only<<<pt_blocks, 256, 0, stream>>>(pts, counts);
        scatter_direct<<<pt_blocks, 256, 0, stream>>>(pts, fts, counts, out);
    }
}